// Round 1
// baseline (373.734 us; speedup 1.0000x reference)
//
#include <hip/hip_runtime.h>
#include <hip/hip_bf16.h>
#include <math.h>

#define NB 8
#define HH 1024
#define WW 1280
#define HW (HH*WW)            // 1310720
#define N4 (HW/4)             // 327680
#define LBINS 2048
#define HBINS 2048
#define NSCENE 8
#define EPSF 1e-8f

// ws layout (32-bit word offsets)
#define WS_HIST    0                        // NB*HBINS u32 = 16384
#define WS_MAXB    (WS_HIST + NB*HBINS)     // 8 u32
#define WS_CNT     (WS_MAXB + NB)           // 8 u32
#define WS_ZERO_WORDS (WS_CNT + NB)         // 16400 words zeroed each call
#define WS_INFO    16400                    // NB*4 u32 {t1, t2, jrel, pad}
#define WS_LOHI    (WS_INFO + NB*4)         // NB*2 f32
#define WS_LUT     (WS_LOHI + NB*2)         // 2048 f32
#define WS_COLLECT 18560                    // NB*cap f32 (256B-aligned)

__device__ __forceinline__ unsigned fkey(float f) {
    unsigned u = __float_as_uint(f);
    return (u & 0x80000000u) ? ~u : (u | 0x80000000u);
}
__device__ __forceinline__ float keyf(unsigned k) {
    unsigned u = (k & 0x80000000u) ? (k & 0x7fffffffu) : ~k;
    return __uint_as_float(u);
}

__global__ __launch_bounds__(256) void k_zero(unsigned* __restrict__ ws) {
    int i = blockIdx.x * 256 + threadIdx.x;
    if (i < WS_ZERO_WORDS) ws[i] = 0u;
}

// per-sample 2048-bin histogram + max (ordered-key atomicMax)
__global__ __launch_bounds__(256) void k_hist(const float* __restrict__ x,
                                              unsigned* __restrict__ ws) {
    __shared__ unsigned lh[HBINS];
    __shared__ unsigned red[256];
    const int s = blockIdx.y;
    for (int i = threadIdx.x; i < HBINS; i += 256) lh[i] = 0u;
    __syncthreads();
    const float4* xs = (const float4*)(x + (size_t)s * HW);
    unsigned mkey = 0u;
    for (int i = blockIdx.x * 256 + threadIdx.x; i < N4; i += gridDim.x * 256) {
        float4 v = xs[i];
        float fv[4] = {v.x, v.y, v.z, v.w};
#pragma unroll
        for (int c = 0; c < 4; ++c) {
            float f = fv[c];
            int b = (int)(f * 2048.0f);
            b = b < 0 ? 0 : (b > 2047 ? 2047 : b);
            atomicAdd(&lh[b], 1u);
            unsigned kk = fkey(f);
            mkey = kk > mkey ? kk : mkey;
        }
    }
    __syncthreads();
    unsigned* gh = ws + WS_HIST + s * HBINS;
    for (int i = threadIdx.x; i < HBINS; i += 256) {
        unsigned c = lh[i];
        if (c) atomicAdd(&gh[i], c);
    }
    red[threadIdx.x] = mkey;
    __syncthreads();
    for (int off = 128; off > 0; off >>= 1) {
        if (threadIdx.x < off) {
            unsigned o = red[threadIdx.x + off];
            if (o > red[threadIdx.x]) red[threadIdx.x] = o;
        }
        __syncthreads();
    }
    if (threadIdx.x == 0) atomicMax(&ws[WS_MAXB + s], red[0]);
}

// per-sample: find bins containing ranks k and k+1 (one wave per sample)
__global__ __launch_bounds__(64) void k_scan(unsigned* __restrict__ ws) {
    const int s = blockIdx.x;
    const unsigned* gh = ws + WS_HIST + s * HBINS;
    int lane = threadIdx.x;
    unsigned cnt[32];
    unsigned run = 0u;
#pragma unroll
    for (int i = 0; i < 32; ++i) { cnt[i] = gh[lane * 32 + i]; run += cnt[i]; }
    unsigned xs = run;
    for (int d = 1; d < 64; d <<= 1) {
        unsigned y = __shfl_up(xs, d);
        if (lane >= d) xs += y;
    }
    unsigned before = xs - run;   // exclusive prefix for this lane's first bin
    const float idxf = 0.02f * (float)(HW - 1);   // f32, mirrors JAX
    const unsigned k = (unsigned)idxf;            // 26214
#pragma unroll
    for (int i = 0; i < 32; ++i) {
        unsigned c = cnt[i];
        unsigned bin = lane * 32 + i;
        if (before <= k && k < before + c) {
            ws[WS_INFO + s * 4 + 0] = bin;
            ws[WS_INFO + s * 4 + 2] = k - before;   // rank of v[k] within collected
        }
        if (before <= k + 1 && k + 1 < before + c) {
            ws[WS_INFO + s * 4 + 1] = bin;
        }
        before += c;
    }
}

// LUT: softplus(mean over scenes) + eps -> cumsum -> normalize to [-1,1]
__global__ __launch_bounds__(64) void k_lut(const float* __restrict__ delta,
                                            float* __restrict__ lut) {
    __shared__ float inc[LBINS];
    int lane = threadIdx.x;
    for (int j = lane; j < LBINS; j += 64) {
        float ssum = 0.0f;
#pragma unroll
        for (int sc = 0; sc < NSCENE; ++sc) ssum += delta[sc * LBINS + j];
        float v = ssum * 0.125f;
        // jax.nn.softplus = logaddexp(x, 0) = max(x,0) + log1p(exp(-|x|))
        inc[j] = fmaxf(v, 0.0f) + log1pf(expf(-fabsf(v))) + EPSF;
    }
    __syncthreads();
    float loc[32];
    float run = 0.0f;
#pragma unroll
    for (int i = 0; i < 32; ++i) { run += inc[lane * 32 + i]; loc[i] = run; }
    float xv = run;
    for (int d = 1; d < 64; d <<= 1) {
        float y = __shfl_up(xv, d);
        if (lane >= d) xv += y;
    }
    float excl = xv - run;
    float total = __shfl(xv, 63);
#pragma unroll
    for (int i = 0; i < 32; ++i) {
        float c = excl + loc[i];
        lut[lane * 32 + i] = c / (total + EPSF) * 2.0f - 1.0f;
    }
}

// gather elements in target bin range (x re-read is L3-resident)
__global__ __launch_bounds__(256) void k_collect(const float* __restrict__ x,
                                                 unsigned* __restrict__ ws, int cap) {
    const int s = blockIdx.y;
    const unsigned t1 = ws[WS_INFO + s * 4 + 0];
    const unsigned t2 = ws[WS_INFO + s * 4 + 1];
    float* coll = (float*)(ws + WS_COLLECT) + (size_t)s * cap;
    unsigned* cnt = ws + WS_CNT + s;
    const float4* xs = (const float4*)(x + (size_t)s * HW);
    for (int i = blockIdx.x * 256 + threadIdx.x; i < N4; i += gridDim.x * 256) {
        float4 v = xs[i];
        float fv[4] = {v.x, v.y, v.z, v.w};
#pragma unroll
        for (int c = 0; c < 4; ++c) {
            float f = fv[c];
            int b = (int)(f * 2048.0f);
            b = b < 0 ? 0 : (b > 2047 ? 2047 : b);
            if ((unsigned)b >= t1 && (unsigned)b <= t2) {
                unsigned p = atomicAdd(cnt, 1u);
                if (p < (unsigned)cap) coll[p] = f;
            }
        }
    }
}

// exact selection by counting among collected candidates
__global__ __launch_bounds__(256) void k_select(unsigned* __restrict__ ws, int cap) {
    __shared__ float sc[8192];
    __shared__ float svk, svk1;
    const int s = blockIdx.x;
    unsigned m = ws[WS_CNT + s];
    if (m > (unsigned)cap) m = (unsigned)cap;
    const float* coll = (const float*)(ws + WS_COLLECT) + (size_t)s * cap;
    const unsigned jrel = ws[WS_INFO + s * 4 + 2];
    const bool useLds = (m <= 8192u);
    if (useLds) {
        for (unsigned i = threadIdx.x; i < m; i += 256) sc[i] = coll[i];
    }
    __syncthreads();
    for (unsigned i = threadIdx.x; i < m; i += 256) {
        float v = useLds ? sc[i] : coll[i];
        unsigned less = 0, eq = 0;
        for (unsigned j = 0; j < m; ++j) {
            float w = useLds ? sc[j] : coll[j];
            less += (w < v) ? 1u : 0u;
            eq += (w == v) ? 1u : 0u;
        }
        if (less <= jrel && jrel < less + eq) svk = v;
        if (less <= jrel + 1 && jrel + 1 < less + eq) svk1 = v;
    }
    __syncthreads();
    if (threadIdx.x == 0) {
        const float idxf = 0.02f * (float)(HW - 1);
        const float frac = idxf - (float)((unsigned)idxf);   // 0.380859375
        float lo = svk * (1.0f - frac) + svk1 * frac;
        float hi = keyf(ws[WS_MAXB + s]);
        float* lh = (float*)(ws + WS_LOHI);
        lh[s * 2 + 0] = lo;
        lh[s * 2 + 1] = hi;
    }
}

// main transform: normalize -> bin -> LUT gather -> write 3 channels
__global__ __launch_bounds__(256) void k_apply(const float* __restrict__ x,
                                               const unsigned* __restrict__ ws,
                                               float* __restrict__ y) {
    __shared__ float slut[LBINS];
    const float* lutg = (const float*)(ws + WS_LUT);
    for (int i = threadIdx.x; i < LBINS; i += 256) slut[i] = lutg[i];
    const int s = blockIdx.y;
    const float* lh = (const float*)(ws + WS_LOHI);
    const float lo = lh[s * 2 + 0];
    const float hi = lh[s * 2 + 1];
    const float denom = hi - lo + EPSF;
    __syncthreads();
    const float4* xs = (const float4*)(x + (size_t)s * HW);
    float4* y0 = (float4*)(y + (size_t)s * 3 * HW);
    float4* y1 = (float4*)(y + (size_t)s * 3 * HW + HW);
    float4* y2 = (float4*)(y + (size_t)s * 3 * HW + 2 * HW);
    for (int i = blockIdx.x * 256 + threadIdx.x; i < N4; i += gridDim.x * 256) {
        float4 v = xs[i];
        float fv[4] = {v.x, v.y, v.z, v.w};
        float ov[4];
#pragma unroll
        for (int c = 0; c < 4; ++c) {
            float xn = (fv[c] - lo) / denom;           // division: mirror reference
            xn = xn < 0.0f ? 0.0f : (xn > 1.0f ? 1.0f : xn);
            float t = xn * 2047.0f;
            int idx = (int)t;
            idx = idx < 0 ? 0 : (idx > 2047 ? 2047 : idx);
            ov[c] = slut[idx];
        }
        float4 o;
        o.x = ov[0]; o.y = ov[1]; o.z = ov[2]; o.w = ov[3];
        y0[i] = o;
        y1[i] = o;
        y2[i] = o;
    }
}

extern "C" void kernel_launch(void* const* d_in, const int* in_sizes, int n_in,
                              void* d_out, int out_size, void* d_ws, size_t ws_size,
                              hipStream_t stream) {
    const float* x = (const float*)d_in[0];
    const float* delta = (const float*)d_in[1];
    float* y = (float*)d_out;
    unsigned* ws = (unsigned*)d_ws;

    int cap = 16384;
    size_t avail_words = ws_size / 4;
    size_t per_sample = avail_words > WS_COLLECT ? (avail_words - WS_COLLECT) / NB : 0;
    if ((size_t)cap > per_sample) cap = (int)per_sample;

    k_zero<<<dim3((WS_ZERO_WORDS + 255) / 256), dim3(256), 0, stream>>>(ws);
    k_hist<<<dim3(64, NB), dim3(256), 0, stream>>>(x, ws);
    k_scan<<<dim3(NB), dim3(64), 0, stream>>>(ws);
    k_lut<<<dim3(1), dim3(64), 0, stream>>>(delta, (float*)(ws + WS_LUT));
    k_collect<<<dim3(32, NB), dim3(256), 0, stream>>>(x, ws, cap);
    k_select<<<dim3(NB), dim3(256), 0, stream>>>(ws, cap);
    k_apply<<<dim3(320, NB), dim3(256), 0, stream>>>(x, ws, y);
}

// Round 7
// 300.440 us; speedup vs baseline: 1.2440x; 1.2440x over previous
//
#include <hip/hip_runtime.h>
#include <hip/hip_bf16.h>
#include <math.h>

#define NB 8
#define HH 1024
#define WW 1280
#define HW (HH*WW)            // 1310720
#define N4 (HW/4)             // 327680
#define LBINS 2048
#define HBINS 2048
#define NSCENE 8
#define EPSF 1e-8f
#define CAPMAX 8192

typedef float f32x4 __attribute__((ext_vector_type(4)));

// ws layout (32-bit word offsets)
#define WS_HIST    0                        // NB*HBINS u32 = 16384
#define WS_MAXB    (WS_HIST + NB*HBINS)     // 8 u32
#define WS_CNT     (WS_MAXB + NB)           // 8 u32
#define WS_ZERO_WORDS (WS_CNT + NB)         // 16400 words zeroed each call
#define WS_INFO    16400                    // NB*4 u32 {t1, t2, jrel, pad}
#define WS_LOHI    (WS_INFO + NB*4)         // NB*2 f32
#define WS_LUT     (WS_LOHI + NB*2)         // 2048 f32
#define WS_COLLECT 18560                    // NB*cap f32

__device__ __forceinline__ unsigned fkey(float f) {
    unsigned u = __float_as_uint(f);
    return (u & 0x80000000u) ? ~u : (u | 0x80000000u);
}
__device__ __forceinline__ float keyf(unsigned k) {
    unsigned u = (k & 0x80000000u) ? (k & 0x7fffffffu) : ~k;
    return __uint_as_float(u);
}

__global__ __launch_bounds__(256) void k_zero(unsigned* __restrict__ ws) {
    int i = blockIdx.x * 256 + threadIdx.x;
    if (i < WS_ZERO_WORDS) ws[i] = 0u;
}

// per-sample 2048-bin histogram + max
__global__ __launch_bounds__(256) void k_hist(const float* __restrict__ x,
                                              unsigned* __restrict__ ws) {
    __shared__ unsigned lh[HBINS];
    __shared__ float redf[4];
    const int s = blockIdx.y;
    for (int i = threadIdx.x; i < HBINS; i += 256) lh[i] = 0u;
    __syncthreads();
    const float4* xs = (const float4*)(x + (size_t)s * HW);
    float mx = -3.4e38f;
    for (int i = blockIdx.x * 256 + threadIdx.x; i < N4; i += gridDim.x * 256) {
        float4 v = xs[i];
        float fv[4] = {v.x, v.y, v.z, v.w};
#pragma unroll
        for (int c = 0; c < 4; ++c) {
            float f = fv[c];
            int b = (int)(f * 2048.0f);
            b = b < 0 ? 0 : (b > 2047 ? 2047 : b);
            atomicAdd(&lh[b], 1u);
            mx = fmaxf(mx, f);
        }
    }
    // wave-reduce max, then cross-wave via LDS
    for (int d = 32; d > 0; d >>= 1) mx = fmaxf(mx, __shfl_down(mx, d));
    __syncthreads();
    if ((threadIdx.x & 63) == 0) redf[threadIdx.x >> 6] = mx;
    __syncthreads();
    unsigned* gh = ws + WS_HIST + s * HBINS;
    for (int i = threadIdx.x; i < HBINS; i += 256) {
        unsigned c = lh[i];
        if (c) atomicAdd(&gh[i], c);
    }
    if (threadIdx.x == 0) {
        float m2 = fmaxf(fmaxf(redf[0], redf[1]), fmaxf(redf[2], redf[3]));
        atomicMax(&ws[WS_MAXB + s], fkey(m2));
    }
}

// per-sample: find bins containing ranks k and k+1 (one wave per sample)
__global__ __launch_bounds__(64) void k_scan(unsigned* __restrict__ ws) {
    const int s = blockIdx.x;
    const unsigned* gh = ws + WS_HIST + s * HBINS;
    int lane = threadIdx.x;
    unsigned cnt[32];
    unsigned run = 0u;
#pragma unroll
    for (int i = 0; i < 32; ++i) { cnt[i] = gh[lane * 32 + i]; run += cnt[i]; }
    unsigned xs = run;
    for (int d = 1; d < 64; d <<= 1) {
        unsigned y = __shfl_up(xs, d);
        if (lane >= d) xs += y;
    }
    unsigned before = xs - run;
    const float idxf = 0.02f * (float)(HW - 1);   // f32, mirrors JAX
    const unsigned k = (unsigned)idxf;            // 26214
#pragma unroll
    for (int i = 0; i < 32; ++i) {
        unsigned c = cnt[i];
        unsigned bin = lane * 32 + i;
        if (before <= k && k < before + c) {
            ws[WS_INFO + s * 4 + 0] = bin;
            ws[WS_INFO + s * 4 + 2] = k - before;   // rank of v[k] within collected
        }
        if (before <= k + 1 && k + 1 < before + c) {
            ws[WS_INFO + s * 4 + 1] = bin;
        }
        before += c;
    }
}

// LUT: softplus(mean over scenes) + eps -> cumsum -> normalize to [-1,1]
__global__ __launch_bounds__(64) void k_lut(const float* __restrict__ delta,
                                            float* __restrict__ lut) {
    __shared__ float inc[LBINS];
    int lane = threadIdx.x;
    for (int j = lane; j < LBINS; j += 64) {
        float ssum = 0.0f;
#pragma unroll
        for (int sc = 0; sc < NSCENE; ++sc) ssum += delta[sc * LBINS + j];
        float v = ssum * 0.125f;
        inc[j] = fmaxf(v, 0.0f) + log1pf(expf(-fabsf(v))) + EPSF;
    }
    __syncthreads();
    float loc[32];
    float run = 0.0f;
#pragma unroll
    for (int i = 0; i < 32; ++i) { run += inc[lane * 32 + i]; loc[i] = run; }
    float xv = run;
    for (int d = 1; d < 64; d <<= 1) {
        float y = __shfl_up(xv, d);
        if (lane >= d) xv += y;
    }
    float excl = xv - run;
    float total = __shfl(xv, 63);
#pragma unroll
    for (int i = 0; i < 32; ++i) {
        float c = excl + loc[i];
        lut[lane * 32 + i] = c / (total + EPSF) * 2.0f - 1.0f;
    }
}

// gather elements in target bin range (x re-read is L2/L3-resident)
__global__ __launch_bounds__(256) void k_collect(const float* __restrict__ x,
                                                 unsigned* __restrict__ ws, int cap) {
    const int s = blockIdx.y;
    const unsigned t1 = ws[WS_INFO + s * 4 + 0];
    const unsigned t2 = ws[WS_INFO + s * 4 + 1];
    float* coll = (float*)(ws + WS_COLLECT) + (size_t)s * cap;
    unsigned* cnt = ws + WS_CNT + s;
    const float4* xs = (const float4*)(x + (size_t)s * HW);
    for (int i = blockIdx.x * 256 + threadIdx.x; i < N4; i += gridDim.x * 256) {
        float4 v = xs[i];
        float fv[4] = {v.x, v.y, v.z, v.w};
#pragma unroll
        for (int c = 0; c < 4; ++c) {
            float f = fv[c];
            int b = (int)(f * 2048.0f);
            b = b < 0 ? 0 : (b > 2047 ? 2047 : b);
            if ((unsigned)b >= t1 && (unsigned)b <= t2) {
                unsigned p = atomicAdd(cnt, 1u);
                if (p < (unsigned)cap) coll[p] = f;
            }
        }
    }
}

// exact selection via 4-pass byte-radix (no compaction), then v[k+1] pass
__global__ __launch_bounds__(256) void k_select(unsigned* __restrict__ ws, int cap) {
    __shared__ unsigned keys[CAPMAX];
    __shared__ unsigned hist[256];
    __shared__ unsigned pfx[256];
    __shared__ unsigned s_bucket, s_r;
    __shared__ unsigned s_L, s_E, s_mg;
    const int s = blockIdx.x;
    const int tid = threadIdx.x;
    unsigned m = ws[WS_CNT + s];
    if (m > (unsigned)cap) m = (unsigned)cap;
    const float* coll = (const float*)(ws + WS_COLLECT) + (size_t)s * cap;
    const unsigned jrel = ws[WS_INFO + s * 4 + 2];

    for (unsigned i = tid; i < m; i += 256) keys[i] = fkey(coll[i]);
    if (tid == 0) { s_L = 0; s_E = 0; s_mg = 0xFFFFFFFFu; }
    __syncthreads();

    unsigned prefix = 0;
    unsigned r = jrel;
    for (int shift = 24; shift >= 0; shift -= 8) {
        hist[tid] = 0u;
        __syncthreads();
        for (unsigned i = tid; i < m; i += 256) {
            unsigned kk = keys[i];
            bool ok = (shift == 24) || ((kk >> (shift + 8)) == prefix);
            if (ok) atomicAdd(&hist[(kk >> shift) & 255u], 1u);
        }
        __syncthreads();
        if (tid < 64) {
            unsigned a0 = hist[tid*4+0], a1 = hist[tid*4+1];
            unsigned a2 = hist[tid*4+2], a3 = hist[tid*4+3];
            unsigned sum = a0 + a1 + a2 + a3;
            unsigned inc = sum;
            for (int d = 1; d < 64; d <<= 1) {
                unsigned y = __shfl_up(inc, d);
                if (tid >= d) inc += y;
            }
            unsigned excl = inc - sum;
            pfx[tid*4+0] = excl;
            pfx[tid*4+1] = excl + a0;
            pfx[tid*4+2] = excl + a0 + a1;
            pfx[tid*4+3] = excl + a0 + a1 + a2;
        }
        __syncthreads();
        {
            unsigned e = pfx[tid], c = hist[tid];
            if (e <= r && r < e + c) { s_bucket = tid; s_r = r - e; }
        }
        __syncthreads();
        prefix = (prefix << 8) | s_bucket;
        r = s_r;
        __syncthreads();
    }
    // prefix == ordered key of v[k]
    const unsigned vk = prefix;
    unsigned lL = 0, lE = 0, lmg = 0xFFFFFFFFu;
    for (unsigned i = tid; i < m; i += 256) {
        unsigned kk = keys[i];
        lL += (kk < vk) ? 1u : 0u;
        lE += (kk == vk) ? 1u : 0u;
        if (kk > vk && kk < lmg) lmg = kk;
    }
    atomicAdd(&s_L, lL);
    atomicAdd(&s_E, lE);
    atomicMin(&s_mg, lmg);
    __syncthreads();
    if (tid == 0) {
        unsigned vk1 = (jrel + 1 < s_L + s_E) ? vk : s_mg;
        float svk = keyf(vk), svk1 = keyf(vk1);
        const float idxf = 0.02f * (float)(HW - 1);
        const float frac = idxf - (float)((unsigned)idxf);   // 0.380859375
        float lo = svk * (1.0f - frac) + svk1 * frac;
        float hi = keyf(ws[WS_MAXB + s]);
        float* lh = (float*)(ws + WS_LOHI);
        lh[s * 2 + 0] = lo;
        lh[s * 2 + 1] = hi;
    }
}

// main transform: normalize -> bin -> LUT gather -> write 3 channels
__global__ __launch_bounds__(256) void k_apply(const float* __restrict__ x,
                                               const unsigned* __restrict__ ws,
                                               float* __restrict__ y) {
    __shared__ float slut[LBINS];
    const float* lutg = (const float*)(ws + WS_LUT);
    for (int i = threadIdx.x; i < LBINS; i += 256) slut[i] = lutg[i];
    const int s = blockIdx.y;
    const float* lh = (const float*)(ws + WS_LOHI);
    const float lo = lh[s * 2 + 0];
    const float hi = lh[s * 2 + 1];
    const float denom = hi - lo + EPSF;
    __syncthreads();
    const f32x4* xs = (const f32x4*)(x + (size_t)s * HW);
    f32x4* y0 = (f32x4*)(y + (size_t)s * 3 * HW);
    f32x4* y1 = (f32x4*)(y + (size_t)s * 3 * HW + HW);
    f32x4* y2 = (f32x4*)(y + (size_t)s * 3 * HW + 2 * HW);
    for (int i = blockIdx.x * 256 + threadIdx.x; i < N4; i += gridDim.x * 256) {
        f32x4 v = xs[i];
        f32x4 o;
#pragma unroll
        for (int c = 0; c < 4; ++c) {
            float xn = (v[c] - lo) / denom;
            xn = xn < 0.0f ? 0.0f : (xn > 1.0f ? 1.0f : xn);
            float t = xn * 2047.0f;
            int idx = (int)t;
            idx = idx < 0 ? 0 : (idx > 2047 ? 2047 : idx);
            o[c] = slut[idx];
        }
        __builtin_nontemporal_store(o, &y0[i]);
        __builtin_nontemporal_store(o, &y1[i]);
        __builtin_nontemporal_store(o, &y2[i]);
    }
}

extern "C" void kernel_launch(void* const* d_in, const int* in_sizes, int n_in,
                              void* d_out, int out_size, void* d_ws, size_t ws_size,
                              hipStream_t stream) {
    const float* x = (const float*)d_in[0];
    const float* delta = (const float*)d_in[1];
    float* y = (float*)d_out;
    unsigned* ws = (unsigned*)d_ws;

    int cap = CAPMAX;
    size_t avail_words = ws_size / 4;
    size_t per_sample = avail_words > WS_COLLECT ? (avail_words - WS_COLLECT) / NB : 0;
    if ((size_t)cap > per_sample) cap = (int)per_sample;

    k_zero<<<dim3((WS_ZERO_WORDS + 255) / 256), dim3(256), 0, stream>>>(ws);
    k_hist<<<dim3(64, NB), dim3(256), 0, stream>>>(x, ws);
    k_scan<<<dim3(NB), dim3(64), 0, stream>>>(ws);
    k_lut<<<dim3(1), dim3(64), 0, stream>>>(delta, (float*)(ws + WS_LUT));
    k_collect<<<dim3(32, NB), dim3(256), 0, stream>>>(x, ws, cap);
    k_select<<<dim3(NB), dim3(256), 0, stream>>>(ws, cap);
    k_apply<<<dim3(320, NB), dim3(256), 0, stream>>>(x, ws, y);
}

// Round 8
// 298.021 us; speedup vs baseline: 1.2541x; 1.0081x over previous
//
#include <hip/hip_runtime.h>
#include <hip/hip_bf16.h>
#include <math.h>

#define NB 8
#define HH 1024
#define WW 1280
#define HW (HH*WW)            // 1310720
#define N4 (HW/4)             // 327680
#define LBINS 2048
#define HBINS 2048
#define NSCENE 8
#define EPSF 1e-8f
#define CAPMAX 8192
#define HBLK 64               // hist blocks per sample

typedef float f32x4 __attribute__((ext_vector_type(4)));

// ws layout (32-bit word offsets) — no pre-zeroing required anywhere
#define WS_PART    0                          // NB*HBLK*HBINS u32 = 1048576 (plain stores)
#define WS_PMAX    (WS_PART + NB*HBLK*HBINS)  // NB*HBLK f32 per-block maxes
#define WS_INFO    (WS_PMAX + NB*HBLK)        // NB*4 u32 {t1, t2, jrel, pad}
#define WS_LOHI    (WS_INFO + NB*4)           // NB*2 f32 {lo, hi}
#define WS_LUT     (WS_LOHI + NB*2)           // 2048 f32
#define WS_CNT     (WS_LUT + LBINS)           // NB u32 (zeroed by k_scan_lut)
#define WS_COLLECT (WS_CNT + NB)              // NB*cap f32

__device__ __forceinline__ unsigned fkey(float f) {
    unsigned u = __float_as_uint(f);
    return (u & 0x80000000u) ? ~u : (u | 0x80000000u);
}
__device__ __forceinline__ float keyf(unsigned k) {
    unsigned u = (k & 0x80000000u) ? (k & 0x7fffffffu) : ~k;
    return __uint_as_float(u);
}

// per-sample 2048-bin histogram + block max -> private partials (no atomics, no zero pass)
__global__ __launch_bounds__(256) void k_hist(const float* __restrict__ x,
                                              unsigned* __restrict__ ws) {
    __shared__ unsigned lh[HBINS];
    __shared__ float redf[4];
    const int s = blockIdx.y;
    for (int i = threadIdx.x; i < HBINS; i += 256) lh[i] = 0u;
    __syncthreads();
    const float4* xs = (const float4*)(x + (size_t)s * HW);
    float mx = -3.4e38f;
    for (int i = blockIdx.x * 256 + threadIdx.x; i < N4; i += HBLK * 256) {
        float4 v = xs[i];
        float fv[4] = {v.x, v.y, v.z, v.w};
#pragma unroll
        for (int c = 0; c < 4; ++c) {
            float f = fv[c];
            int b = (int)(f * 2048.0f);
            b = b < 0 ? 0 : (b > 2047 ? 2047 : b);
            atomicAdd(&lh[b], 1u);
            mx = fmaxf(mx, f);
        }
    }
    for (int d = 32; d > 0; d >>= 1) mx = fmaxf(mx, __shfl_down(mx, d));
    if ((threadIdx.x & 63) == 0) redf[threadIdx.x >> 6] = mx;
    __syncthreads();
    unsigned* myp = ws + WS_PART + ((size_t)s * HBLK + blockIdx.x) * HBINS;
    for (int i = threadIdx.x; i < HBINS; i += 256) myp[i] = lh[i];
    if (threadIdx.x == 0) {
        float m2 = fmaxf(fmaxf(redf[0], redf[1]), fmaxf(redf[2], redf[3]));
        ((float*)(ws + WS_PMAX))[s * HBLK + blockIdx.x] = m2;
    }
}

// blocks 0..7: per-sample partial-sum + prefix-scan -> target bins, jrel, hi, cnt=0
// block 8: LUT (softplus of scene-mean -> cumsum -> normalize to [-1,1])
__global__ __launch_bounds__(256) void k_scan_lut(unsigned* __restrict__ ws,
                                                  const float* __restrict__ delta) {
    __shared__ unsigned su[256];
    __shared__ float sf[256];
    const int s = blockIdx.x;
    const int tid = threadIdx.x;
    if (s == NB) {
        float inc[8];
        float run = 0.0f;
#pragma unroll
        for (int i = 0; i < 8; ++i) {
            int j = tid * 8 + i;
            float ssum = 0.0f;
#pragma unroll
            for (int sc = 0; sc < NSCENE; ++sc) ssum += delta[sc * LBINS + j];
            float v = ssum * 0.125f;
            // jax.nn.softplus = max(x,0) + log1p(exp(-|x|))
            run += fmaxf(v, 0.0f) + log1pf(expf(-fabsf(v))) + EPSF;
            inc[i] = run;   // local inclusive
        }
        sf[tid] = run;
        __syncthreads();
        for (int d = 1; d < 256; d <<= 1) {       // Hillis-Steele over thread totals
            float add = (tid >= d) ? sf[tid - d] : 0.0f;
            __syncthreads();
            sf[tid] += add;
            __syncthreads();
        }
        float excl = sf[tid] - run;
        float total = sf[255];
        float* lut = (float*)(ws + WS_LUT);
#pragma unroll
        for (int i = 0; i < 8; ++i)
            lut[tid * 8 + i] = (excl + inc[i]) / (total + EPSF) * 2.0f - 1.0f;
        return;
    }
    // sum 64 partials per bin (8 consecutive bins per thread)
    const unsigned* part = ws + WS_PART + (size_t)s * HBLK * HBINS;
    unsigned cnt[8];
    unsigned run = 0u;
#pragma unroll
    for (int i = 0; i < 8; ++i) {
        int j = tid * 8 + i;
        unsigned c = 0;
        for (int b = 0; b < HBLK; ++b) c += part[b * HBINS + j];
        cnt[i] = c;
        run += c;
    }
    su[tid] = run;
    __syncthreads();
    for (int d = 1; d < 256; d <<= 1) {
        unsigned add = (tid >= d) ? su[tid - d] : 0u;
        __syncthreads();
        su[tid] += add;
        __syncthreads();
    }
    unsigned before = su[tid] - run;
    const float idxf = 0.02f * (float)(HW - 1);   // f32, mirrors JAX
    const unsigned k = (unsigned)idxf;            // 26214
#pragma unroll
    for (int i = 0; i < 8; ++i) {
        unsigned c = cnt[i];
        unsigned bin = tid * 8 + i;
        if (before <= k && k < before + c) {
            ws[WS_INFO + s * 4 + 0] = bin;
            ws[WS_INFO + s * 4 + 2] = k - before;   // rank of v[k] within collected
        }
        if (before <= k + 1 && k + 1 < before + c) {
            ws[WS_INFO + s * 4 + 1] = bin;
        }
        before += c;
    }
    if (tid < 64) {   // exactly wave 0
        float mx = ((const float*)(ws + WS_PMAX))[s * HBLK + tid];
        for (int d = 32; d > 0; d >>= 1) mx = fmaxf(mx, __shfl_down(mx, d));
        if (tid == 0) {
            ((float*)(ws + WS_LOHI))[s * 2 + 1] = mx;   // hi = max
            ws[WS_CNT + s] = 0u;
        }
    }
}

// gather elements in target bin range (x re-read is L2/L3-resident)
__global__ __launch_bounds__(256) void k_collect(const float* __restrict__ x,
                                                 unsigned* __restrict__ ws, int cap) {
    const int s = blockIdx.y;
    const unsigned t1 = ws[WS_INFO + s * 4 + 0];
    const unsigned t2 = ws[WS_INFO + s * 4 + 1];
    float* coll = (float*)(ws + WS_COLLECT) + (size_t)s * cap;
    unsigned* cnt = ws + WS_CNT + s;
    const float4* xs = (const float4*)(x + (size_t)s * HW);
    for (int i = blockIdx.x * 256 + threadIdx.x; i < N4; i += gridDim.x * 256) {
        float4 v = xs[i];
        float fv[4] = {v.x, v.y, v.z, v.w};
#pragma unroll
        for (int c = 0; c < 4; ++c) {
            float f = fv[c];
            int b = (int)(f * 2048.0f);
            b = b < 0 ? 0 : (b > 2047 ? 2047 : b);
            if ((unsigned)b >= t1 && (unsigned)b <= t2) {
                unsigned p = atomicAdd(cnt, 1u);
                if (p < (unsigned)cap) coll[p] = f;
            }
        }
    }
}

// exact selection via 4-pass byte-radix, then v[k+1] pass; writes lo
__global__ __launch_bounds__(256) void k_select(unsigned* __restrict__ ws, int cap) {
    __shared__ unsigned keys[CAPMAX];
    __shared__ unsigned hist[256];
    __shared__ unsigned pfx[256];
    __shared__ unsigned s_bucket, s_r;
    __shared__ unsigned s_L, s_E, s_mg;
    const int s = blockIdx.x;
    const int tid = threadIdx.x;
    unsigned m = ws[WS_CNT + s];
    if (m > (unsigned)cap) m = (unsigned)cap;
    const float* coll = (const float*)(ws + WS_COLLECT) + (size_t)s * cap;
    const unsigned jrel = ws[WS_INFO + s * 4 + 2];

    for (unsigned i = tid; i < m; i += 256) keys[i] = fkey(coll[i]);
    if (tid == 0) { s_L = 0; s_E = 0; s_mg = 0xFFFFFFFFu; }
    __syncthreads();

    unsigned prefix = 0;
    unsigned r = jrel;
    for (int shift = 24; shift >= 0; shift -= 8) {
        hist[tid] = 0u;
        __syncthreads();
        for (unsigned i = tid; i < m; i += 256) {
            unsigned kk = keys[i];
            bool ok = (shift == 24) || ((kk >> (shift + 8)) == prefix);
            if (ok) atomicAdd(&hist[(kk >> shift) & 255u], 1u);
        }
        __syncthreads();
        if (tid < 64) {
            unsigned a0 = hist[tid*4+0], a1 = hist[tid*4+1];
            unsigned a2 = hist[tid*4+2], a3 = hist[tid*4+3];
            unsigned sum = a0 + a1 + a2 + a3;
            unsigned inc = sum;
            for (int d = 1; d < 64; d <<= 1) {
                unsigned y = __shfl_up(inc, d);
                if (tid >= d) inc += y;
            }
            unsigned excl = inc - sum;
            pfx[tid*4+0] = excl;
            pfx[tid*4+1] = excl + a0;
            pfx[tid*4+2] = excl + a0 + a1;
            pfx[tid*4+3] = excl + a0 + a1 + a2;
        }
        __syncthreads();
        {
            unsigned e = pfx[tid], c = hist[tid];
            if (e <= r && r < e + c) { s_bucket = tid; s_r = r - e; }
        }
        __syncthreads();
        prefix = (prefix << 8) | s_bucket;
        r = s_r;
        __syncthreads();
    }
    const unsigned vk = prefix;
    unsigned lL = 0, lE = 0, lmg = 0xFFFFFFFFu;
    for (unsigned i = tid; i < m; i += 256) {
        unsigned kk = keys[i];
        lL += (kk < vk) ? 1u : 0u;
        lE += (kk == vk) ? 1u : 0u;
        if (kk > vk && kk < lmg) lmg = kk;
    }
    atomicAdd(&s_L, lL);
    atomicAdd(&s_E, lE);
    atomicMin(&s_mg, lmg);
    __syncthreads();
    if (tid == 0) {
        unsigned vk1 = (jrel + 1 < s_L + s_E) ? vk : s_mg;
        float svk = keyf(vk), svk1 = keyf(vk1);
        const float idxf = 0.02f * (float)(HW - 1);
        const float frac = idxf - (float)((unsigned)idxf);   // 0.380859375
        ((float*)(ws + WS_LOHI))[s * 2 + 0] = svk * (1.0f - frac) + svk1 * frac;
    }
}

// main transform: normalize -> bin -> LUT gather -> write 3 channels (nontemporal)
__global__ __launch_bounds__(256) void k_apply(const float* __restrict__ x,
                                               const unsigned* __restrict__ ws,
                                               float* __restrict__ y) {
    __shared__ float slut[LBINS];
    const float* lutg = (const float*)(ws + WS_LUT);
    for (int i = threadIdx.x; i < LBINS; i += 256) slut[i] = lutg[i];
    const int s = blockIdx.y;
    const float* lh = (const float*)(ws + WS_LOHI);
    const float lo = lh[s * 2 + 0];
    const float hi = lh[s * 2 + 1];
    const float denom = hi - lo + EPSF;
    __syncthreads();
    const f32x4* xs = (const f32x4*)(x + (size_t)s * HW);
    f32x4* y0 = (f32x4*)(y + (size_t)s * 3 * HW);
    f32x4* y1 = (f32x4*)(y + (size_t)s * 3 * HW + HW);
    f32x4* y2 = (f32x4*)(y + (size_t)s * 3 * HW + 2 * HW);
    for (int i = blockIdx.x * 256 + threadIdx.x; i < N4; i += gridDim.x * 256) {
        f32x4 v = xs[i];
        f32x4 o;
#pragma unroll
        for (int c = 0; c < 4; ++c) {
            float xn = (v[c] - lo) / denom;
            xn = xn < 0.0f ? 0.0f : (xn > 1.0f ? 1.0f : xn);
            float t = xn * 2047.0f;
            int idx = (int)t;
            idx = idx < 0 ? 0 : (idx > 2047 ? 2047 : idx);
            o[c] = slut[idx];
        }
        __builtin_nontemporal_store(o, &y0[i]);
        __builtin_nontemporal_store(o, &y1[i]);
        __builtin_nontemporal_store(o, &y2[i]);
    }
}

extern "C" void kernel_launch(void* const* d_in, const int* in_sizes, int n_in,
                              void* d_out, int out_size, void* d_ws, size_t ws_size,
                              hipStream_t stream) {
    const float* x = (const float*)d_in[0];
    const float* delta = (const float*)d_in[1];
    float* y = (float*)d_out;
    unsigned* ws = (unsigned*)d_ws;

    int cap = CAPMAX;
    size_t avail_words = ws_size / 4;
    size_t per_sample = avail_words > WS_COLLECT ? (avail_words - WS_COLLECT) / NB : 0;
    if ((size_t)cap > per_sample) cap = (int)per_sample;

    k_hist<<<dim3(HBLK, NB), dim3(256), 0, stream>>>(x, ws);
    k_scan_lut<<<dim3(NB + 1), dim3(256), 0, stream>>>(ws, delta);
    k_collect<<<dim3(64, NB), dim3(256), 0, stream>>>(x, ws, cap);
    k_select<<<dim3(NB), dim3(256), 0, stream>>>(ws, cap);
    k_apply<<<dim3(320, NB), dim3(256), 0, stream>>>(x, ws, y);
}